// Round 4
// baseline (378.246 us; speedup 1.0000x reference)
//
#include <hip/hip_runtime.h>
#include <cstdint>

// NewsEncoder: B=8192, L=64, D=256, H=8, DH=32, VOCAB=50000.
// Algebraic restructure eliminates Q/K/V/hidden materialization entirely.
// Workspace (floats/ushorts): m[8*256] f32 | xbar[8192*256] f32 (aliased by cbar) |
//   gqk[8192*512] f32 | cbf[8192*2048] bf16 (c then y, aliased per-sample)  => ~56 MB
// kernel_launch guards ws_size: if insufficient, launches nothing (clean
// validation failure instead of OOB-write GPU wedge -> diagnostic).

using f32x4  = __attribute__((ext_vector_type(4))) float;
using bf16x8 = __attribute__((ext_vector_type(8))) short;

__device__ __forceinline__ unsigned int pack2bf(float a, float b) {
  unsigned int ua = __builtin_bit_cast(unsigned int, a);
  unsigned int ub = __builtin_bit_cast(unsigned int, b);
  ua = (ua + 0x7fffu + ((ua >> 16) & 1u)) >> 16;   // RTNE to bf16
  ub = (ub + 0x7fffu + ((ub >> 16) & 1u)) >> 16;
  return ua | (ub << 16);
}
__device__ __forceinline__ unsigned short bf1(float a) {
  unsigned int ua = __builtin_bit_cast(unsigned int, a);
  ua = (ua + 0x7fffu + ((ua >> 16) & 1u)) >> 16;
  return (unsigned short)ua;
}
__device__ __forceinline__ float ubf(unsigned int u) {
  return __builtin_bit_cast(float, u << 16);
}

// ---- prep: WOd[d] = sum_d' WO[d][d']*dw[d'];  m[h][d] = sum_j WV[d][h*32+j]*WOd[h*32+j]
__global__ __launch_bounds__(256) void prep_kernel(const float* __restrict__ WV,
                                                   const float* __restrict__ WO,
                                                   const float* __restrict__ dw,
                                                   float* __restrict__ m_ws) {
  __shared__ float wod[256];
  const int t = threadIdx.x;
  float acc = 0.f;
  for (int e = 0; e < 256; e += 4) {
    const float4 w4 = *(const float4*)(WO + (size_t)t * 256 + e);
    const float4 d4 = *(const float4*)(dw + e);
    acc += w4.x * d4.x + w4.y * d4.y + w4.z * d4.z + w4.w * d4.w;
  }
  wod[t] = acc;
  __syncthreads();
  for (int h = 0; h < 8; ++h) {
    float a = 0.f;
    for (int j = 0; j < 32; j += 4) {
      const float4 w4 = *(const float4*)(WV + (size_t)t * 256 + h * 32 + j);
      a += w4.x * wod[h*32+j] + w4.y * wod[h*32+j+1] + w4.z * wod[h*32+j+2] + w4.w * wod[h*32+j+3];
    }
    m_ws[h * 256 + t] = a;
  }
}

// ---- K1: xbar[b][d] = mean_l emb[tok[b][l]][d]
__global__ __launch_bounds__(256) void xbar_kernel(const int* __restrict__ tokens,
                                                   const float* __restrict__ emb,
                                                   float* __restrict__ xbar) {
  __shared__ int tok[64];
  const int b = blockIdx.x, t = threadIdx.x;
  if (t < 64) tok[t] = tokens[b * 64 + t];
  __syncthreads();
  float acc = 0.f;
#pragma unroll 8
  for (int r = 0; r < 64; ++r) acc += emb[(size_t)tok[r] * 256 + t];
  xbar[(size_t)b * 256 + t] = acc * (1.f / 64.f);
}

// ---- generic tiled GEMM: C[64-tile][64-tile] = A[M,K]@B[K,N], row-major, grid.z strides
// A_BF16: A stored as bf16 (ushort), lda/aZ in elements.
template <bool A_BF16>
__global__ __launch_bounds__(256) void gemm_t(const void* __restrict__ Av,
                                              const float* __restrict__ Bm,
                                              float* __restrict__ C,
                                              int N, int K, int lda, int ldb, int ldc,
                                              long aZ, long bZ, long cZ) {
  __shared__ float As[64 * 20];
  __shared__ float Bs[16 * 68];
  const int t = threadIdx.x;
  const int bm = blockIdx.x * 64, bn = blockIdx.y * 64;
  Bm += (long)blockIdx.z * bZ;
  C  += (long)blockIdx.z * cZ;
  const int ty = t >> 4, tx = t & 15;
  const int lr = t >> 2, lj = (t & 3) * 4;   // A staging: row lr, k-offset lj
  const int lk = t >> 4, ln = (t & 15) * 4;  // B staging
  float acc[4][4] = {};
  for (int k0 = 0; k0 < K; k0 += 16) {
    float4 a4;
    if constexpr (A_BF16) {
      const unsigned short* A = (const unsigned short*)Av + (long)blockIdx.z * aZ;
      const uint2 au = *(const uint2*)(A + (size_t)(bm + lr) * lda + k0 + lj);
      a4 = make_float4(ubf(au.x & 0xffffu), ubf(au.x >> 16),
                       ubf(au.y & 0xffffu), ubf(au.y >> 16));
    } else {
      const float* A = (const float*)Av + (long)blockIdx.z * aZ;
      a4 = *(const float4*)(A + (size_t)(bm + lr) * lda + k0 + lj);
    }
    float4 b4 = make_float4(0.f, 0.f, 0.f, 0.f);
    if (bn + ln < N) b4 = *(const float4*)(Bm + (size_t)(k0 + lk) * ldb + bn + ln);
    __syncthreads();
    *(float4*)(As + lr * 20 + lj) = a4;
    *(float4*)(Bs + lk * 68 + ln) = b4;
    __syncthreads();
#pragma unroll
    for (int k = 0; k < 16; ++k) {
      const float a0 = As[(4*ty+0)*20 + k];
      const float a1 = As[(4*ty+1)*20 + k];
      const float a2 = As[(4*ty+2)*20 + k];
      const float a3 = As[(4*ty+3)*20 + k];
      const float4 bb = *(const float4*)(Bs + k * 68 + 4 * tx);
      acc[0][0]+=a0*bb.x; acc[0][1]+=a0*bb.y; acc[0][2]+=a0*bb.z; acc[0][3]+=a0*bb.w;
      acc[1][0]+=a1*bb.x; acc[1][1]+=a1*bb.y; acc[1][2]+=a1*bb.z; acc[1][3]+=a1*bb.w;
      acc[2][0]+=a2*bb.x; acc[2][1]+=a2*bb.y; acc[2][2]+=a2*bb.z; acc[2][3]+=a2*bb.w;
      acc[3][0]+=a3*bb.x; acc[3][1]+=a3*bb.y; acc[3][2]+=a3*bb.z; acc[3][3]+=a3*bb.w;
    }
  }
  if (bn + 4 * tx < N) {
#pragma unroll
    for (int i = 0; i < 4; ++i) {
      *(float4*)(C + (size_t)(bm + 4*ty + i) * ldc + bn + 4*tx) =
          make_float4(acc[i][0], acc[i][1], acc[i][2], acc[i][3]);
    }
  }
}

// ---- K3: c[b][h*256+d] = sum_j WK[d][h*32+j]*gq[b][h*32+j] + WQ[d][h*32+j]*gk[b][h*32+j]
// Output stored as bf16 into cbf.
__global__ __launch_bounds__(256) void c_kernel(const float* __restrict__ gqk,
                                                const float* __restrict__ WQ,
                                                const float* __restrict__ WK,
                                                unsigned short* __restrict__ cbf) {
  __shared__ float Gq[64 * 36], Gk[64 * 36], Wk[64 * 36], Wq[64 * 36];
  const int t = threadIdx.x;
  const int bs = blockIdx.x * 64, h = blockIdx.y, d0 = blockIdx.z * 64;
  {
    const int s = t >> 2, j8 = (t & 3) * 8;
    const float4 q0 = *(const float4*)(gqk + (size_t)(bs+s)*512 + h*32 + j8);
    const float4 q1 = *(const float4*)(gqk + (size_t)(bs+s)*512 + h*32 + j8 + 4);
    const float4 k0 = *(const float4*)(gqk + (size_t)(bs+s)*512 + 256 + h*32 + j8);
    const float4 k1 = *(const float4*)(gqk + (size_t)(bs+s)*512 + 256 + h*32 + j8 + 4);
    *(float4*)(Gq + s*36 + j8)     = q0;
    *(float4*)(Gq + s*36 + j8 + 4) = q1;
    *(float4*)(Gk + s*36 + j8)     = k0;
    *(float4*)(Gk + s*36 + j8 + 4) = k1;
    const float4 wk0 = *(const float4*)(WK + (size_t)(d0+s)*256 + h*32 + j8);
    const float4 wk1 = *(const float4*)(WK + (size_t)(d0+s)*256 + h*32 + j8 + 4);
    const float4 wq0 = *(const float4*)(WQ + (size_t)(d0+s)*256 + h*32 + j8);
    const float4 wq1 = *(const float4*)(WQ + (size_t)(d0+s)*256 + h*32 + j8 + 4);
    *(float4*)(Wk + s*36 + j8)     = wk0;
    *(float4*)(Wk + s*36 + j8 + 4) = wk1;
    *(float4*)(Wq + s*36 + j8)     = wq0;
    *(float4*)(Wq + s*36 + j8 + 4) = wq1;
  }
  __syncthreads();
  const int ty = t >> 4, tx = t & 15;
  float acc[4][4] = {};
#pragma unroll 4
  for (int k = 0; k < 32; ++k) {
    float a[4], bb[4];
#pragma unroll
    for (int i = 0; i < 4; ++i) a[i]  = Gq[(4*ty+i)*36 + k];
#pragma unroll
    for (int j = 0; j < 4; ++j) bb[j] = Wk[(4*tx+j)*36 + k];
#pragma unroll
    for (int i = 0; i < 4; ++i)
#pragma unroll
      for (int j = 0; j < 4; ++j) acc[i][j] += a[i] * bb[j];
  }
#pragma unroll 4
  for (int k = 0; k < 32; ++k) {
    float a[4], bb[4];
#pragma unroll
    for (int i = 0; i < 4; ++i) a[i]  = Gk[(4*ty+i)*36 + k];
#pragma unroll
    for (int j = 0; j < 4; ++j) bb[j] = Wq[(4*tx+j)*36 + k];
#pragma unroll
    for (int i = 0; i < 4; ++i)
#pragma unroll
      for (int j = 0; j < 4; ++j) acc[i][j] += a[i] * bb[j];
  }
#pragma unroll
  for (int i = 0; i < 4; ++i) {
    uint2 pk;
    pk.x = pack2bf(acc[i][0], acc[i][1]);
    pk.y = pack2bf(acc[i][2], acc[i][3]);
    *(uint2*)(cbf + (size_t)(bs + 4*ty + i) * 2048 + h*256 + d0 + 4*tx) = pk;
  }
}

// ---- K4: per-sample main kernel. Reads c[b] (bf16) from cbf, writes y[b] (bf16) over it.
__global__ __launch_bounds__(256) void main_kernel(const int* __restrict__ tokens,
                                                   const float* __restrict__ emb,
                                                   const float* __restrict__ m_ws,
                                                   const float* __restrict__ dense_b,
                                                   unsigned short* __restrict__ cbf) {
  __shared__ int tok[64];
  __shared__ unsigned short xl[64 * 264];   // x as bf16, row stride 264 (132 dwords)
  __shared__ unsigned short cm[16 * 264];   // rows 0..7 = c[h][d], 8..15 = m[h][d] (bf16)
  __shared__ float wslds[64 * 20];          // cols 0..7 = w logits->softmax, 8..15 = s
  __shared__ float coef[64 * 8];
  const int t = threadIdx.x;
  const int b = blockIdx.x;
  if (t < 64) tok[t] = tokens[b * 64 + t];
  __syncthreads();
  {
    unsigned int* xu = (unsigned int*)xl;
#pragma unroll 4
    for (int it = 0; it < 32; ++it) {
      const int idx = it * 256 + t;          // 0..8191
      const int row = idx >> 7, cp = idx & 127;
      const float2 v = *(const float2*)(emb + (size_t)tok[row] * 256 + cp * 2);
      xu[row * 132 + cp] = pack2bf(v.x, v.y);
    }
    unsigned int* cu = (unsigned int*)cm;
    const unsigned int* cbu = (const unsigned int*)(cbf + (size_t)b * 2048);
#pragma unroll
    for (int it = 0; it < 8; ++it) {
      const int idx = it * 256 + t;          // 0..2047
      const int r = idx >> 7, cp = idx & 127;
      if (r < 8) {
        cu[r * 132 + cp] = cbu[r * 128 + cp];   // c already bf16
      } else {
        const float2 v = *(const float2*)(m_ws + (size_t)(r - 8) * 256 + cp * 2);
        cu[r * 132 + cp] = pack2bf(v.x, v.y);
      }
    }
  }
  __syncthreads();
  // [W | S] = X[64,256] @ CM^T[256,16] via mfma 16x16x32 bf16 (1 tile per wave)
  {
    const int wv = t >> 6, l = t & 63;
    const int arow = 16 * wv + (l & 15);
    const int g = l >> 4;
    f32x4 acc = {0.f, 0.f, 0.f, 0.f};
#pragma unroll
    for (int kk = 0; kk < 8; ++kk) {
      const bf16x8 a  = *(const bf16x8*)(xl + arow * 264 + kk * 32 + g * 8);
      const bf16x8 bb = *(const bf16x8*)(cm + (l & 15) * 264 + kk * 32 + g * 8);
      acc = __builtin_amdgcn_mfma_f32_16x16x32_bf16(a, bb, acc, 0, 0, 0);
    }
    const int col = l & 15;
#pragma unroll
    for (int i = 0; i < 4; ++i)
      wslds[(16 * wv + g * 4 + i) * 20 + col] = acc[i];
  }
  __syncthreads();
  // per-head softmax over seq (wave w handles heads 2w, 2w+1; lane = seq pos)
  {
    const int wv = t >> 6, l = t & 63;
#pragma unroll
    for (int hh = 0; hh < 2; ++hh) {
      const int h = 2 * wv + hh;
      const float v = wslds[l * 20 + h];
      float mx = v;
#pragma unroll
      for (int sft = 32; sft; sft >>= 1) mx = fmaxf(mx, __shfl_xor(mx, sft));
      const float e = expf(v - mx);
      float sm = e;
#pragma unroll
      for (int sft = 32; sft; sft >>= 1) sm += __shfl_xor(sm, sft);
      wslds[l * 20 + h] = e / sm;
    }
  }
  __syncthreads();
  // scores softmax + coef (single wave)
  if (t < 64) {
    const int l = t;
    float p[8], sv[8];
#pragma unroll
    for (int h = 0; h < 8; ++h) { p[h] = wslds[l*20 + h]; sv[h] = wslds[l*20 + 8 + h]; }
    float sc = dense_b[0];
#pragma unroll
    for (int h = 0; h < 8; ++h) sc += p[h] * sv[h];
    float mx = sc;
#pragma unroll
    for (int sft = 32; sft; sft >>= 1) mx = fmaxf(mx, __shfl_xor(mx, sft));
    const float e = expf(sc - mx);
    float sm = e;
#pragma unroll
    for (int sft = 32; sft; sft >>= 1) sm += __shfl_xor(sm, sft);
    const float attn = e / sm;
    *(float4*)(coef + l * 8)     = make_float4(attn*p[0], attn*p[1], attn*p[2], attn*p[3]);
    *(float4*)(coef + l * 8 + 4) = make_float4(attn*p[4], attn*p[5], attn*p[6], attn*p[7]);
  }
  __syncthreads();
  // y[h][d] = sum_l coef[l][h] * x[l][d]; wave w covers l in [16w,16w+16), lane owns 4 d's
  {
    const int wv = t >> 6, lane = t & 63;
    const unsigned int* xu = (const unsigned int*)xl;
    float yacc[8][4] = {};
#pragma unroll
    for (int li = 0; li < 16; ++li) {
      const int l = 16 * wv + li;
      const uint2 xv = *(const uint2*)(xu + l * 132 + lane * 2);
      const float x0 = ubf(xv.x & 0xffffu);
      const float x1 = ubf(xv.x >> 16);
      const float x2 = ubf(xv.y & 0xffffu);
      const float x3 = ubf(xv.y >> 16);
      const float4 c0 = *(const float4*)(coef + l * 8);
      const float4 c1 = *(const float4*)(coef + l * 8 + 4);
      yacc[0][0]+=c0.x*x0; yacc[0][1]+=c0.x*x1; yacc[0][2]+=c0.x*x2; yacc[0][3]+=c0.x*x3;
      yacc[1][0]+=c0.y*x0; yacc[1][1]+=c0.y*x1; yacc[1][2]+=c0.y*x2; yacc[1][3]+=c0.y*x3;
      yacc[2][0]+=c0.z*x0; yacc[2][1]+=c0.z*x1; yacc[2][2]+=c0.z*x2; yacc[2][3]+=c0.z*x3;
      yacc[3][0]+=c0.w*x0; yacc[3][1]+=c0.w*x1; yacc[3][2]+=c0.w*x2; yacc[3][3]+=c0.w*x3;
      yacc[4][0]+=c1.x*x0; yacc[4][1]+=c1.x*x1; yacc[4][2]+=c1.x*x2; yacc[4][3]+=c1.x*x3;
      yacc[5][0]+=c1.y*x0; yacc[5][1]+=c1.y*x1; yacc[5][2]+=c1.y*x2; yacc[5][3]+=c1.y*x3;
      yacc[6][0]+=c1.z*x0; yacc[6][1]+=c1.z*x1; yacc[6][2]+=c1.z*x2; yacc[6][3]+=c1.z*x3;
      yacc[7][0]+=c1.w*x0; yacc[7][1]+=c1.w*x1; yacc[7][2]+=c1.w*x2; yacc[7][3]+=c1.w*x3;
    }
    __syncthreads();                       // all x reads done; reuse xl as partials
    float* part = (float*)xl;              // [4][8][256]
#pragma unroll
    for (int h = 0; h < 8; ++h) {
      *(float4*)(part + (wv * 8 + h) * 256 + lane * 4) =
          make_float4(yacc[h][0], yacc[h][1], yacc[h][2], yacc[h][3]);
    }
  }
  __syncthreads();
  {
    const float* part = (const float*)xl;
#pragma unroll
    for (int h = 0; h < 8; ++h) {
      const float s = part[(0*8+h)*256 + t] + part[(1*8+h)*256 + t] +
                      part[(2*8+h)*256 + t] + part[(3*8+h)*256 + t];
      cbf[(size_t)b * 2048 + h * 256 + t] = bf1(s);   // y[b][h][d] as bf16
    }
  }
}

extern "C" void kernel_launch(void* const* d_in, const int* in_sizes, int n_in,
                              void* d_out, int out_size, void* d_ws, size_t ws_size,
                              hipStream_t stream) {
  const int*   tokens = (const int*)d_in[0];
  const float* emb    = (const float*)d_in[1];
  const float* WQ     = (const float*)d_in[2];
  const float* WK     = (const float*)d_in[3];
  const float* WV     = (const float*)d_in[4];
  const float* WO     = (const float*)d_in[5];
  const float* dw     = (const float*)d_in[6];
  const float* db     = (const float*)d_in[7];
  float* out = (float*)d_out;

  // Required workspace: m(2048 f32) + xbar(2M f32) + gqk(4M f32) + cbf(16M bf16)
  const size_t need_bytes = (size_t)(2048 + 8192*256 + 8192*512) * 4
                          + (size_t)8192 * 2048 * 2;
  if (ws_size < need_bytes) return;  // deterministic no-op: clean validation
                                     // failure (diagnostic) instead of OOB wedge

  float* ws    = (float*)d_ws;
  float* m_ws  = ws;                                   // 2048 f32
  float* xbar  = ws + 2048;                            // 8192*256 f32 (8 MB)
  float* gqk   = xbar + (size_t)8192 * 256;            // 8192*512 f32 (16 MB)
  unsigned short* cbf = (unsigned short*)(gqk + (size_t)8192 * 512); // 8192*2048 bf16 (32 MB)
  float* cbar  = xbar;                                 // aliases xbar (dead after c_kernel)

  prep_kernel<<<dim3(1), dim3(256), 0, stream>>>(WV, WO, dw, m_ws);
  xbar_kernel<<<dim3(8192), dim3(256), 0, stream>>>(tokens, emb, xbar);
  // gq | gk = xbar @ WQ | WK   -> gqk [8192][512]
  gemm_t<false><<<dim3(128, 4, 1), dim3(256), 0, stream>>>(xbar, WQ, gqk,       256, 256, 256, 256, 512, 0l, 0l, 0l);
  gemm_t<false><<<dim3(128, 4, 1), dim3(256), 0, stream>>>(xbar, WK, gqk + 256, 256, 256, 256, 256, 512, 0l, 0l, 0l);
  // c [8192][8][256] as bf16
  c_kernel<<<dim3(128, 8, 4), dim3(256), 0, stream>>>(gqk, WQ, WK, cbf);
  // main per-sample: logits, softmaxes, y (overwrites c, bf16)
  main_kernel<<<dim3(8192), dim3(256), 0, stream>>>(tokens, emb, m_ws, db, cbf);
  // cbar[b][h*32+n] = sum_e y[b][h][e] * WV[e][h*32+n]   (A = bf16 y)
  gemm_t<true><<<dim3(128, 1, 8), dim3(256), 0, stream>>>(cbf, WV, cbar, 32, 256, 2048, 256, 256, 256l, 32l, 32l);
  // out = cbar @ WO
  gemm_t<false><<<dim3(128, 4, 1), dim3(256), 0, stream>>>(cbar, WO, out, 256, 256, 256, 256, 256, 0l, 0l, 0l);
}